// Round 5
// baseline (178.376 us; speedup 1.0000x reference)
//
#include <hip/hip_runtime.h>
#include <hip/hip_fp16.h>

static constexpr int Hh = 384;
static constexpr int Ww = 1280;
static constexpr int HW = Hh * Ww;            // 491520
static constexpr int TILE = 64;               // output tile side
static constexpr int T = 24;                  // ALL steps fused, single launch
static constexpr int R = TILE + 2 * T;        // 112: region side incl. 24-step halo
static constexpr int RR = R * R;              // 12544
static constexpr int ISIDE = R - 2;           // 110
static constexpr int NINT = ISIDE * ISIDE;    // 12100 interior pixels
static constexpr int BLOCK = 1024;
static constexpr int PPQ = (RR + BLOCK - 1) / BLOCK;    // 13 region px / thread
static constexpr int PPI = (NINT + BLOCK - 1) / BLOCK;  // 12 interior px / thread
static constexpr int TI = Hh / TILE;          // 6
static constexpr int TJ = Ww / TILE;          // 20
static constexpr int GRID = 2 * TI * TJ;      // 240 fully independent blocks
static constexpr int NXCD = 8;
static constexpr int CHUNK = GRID / NXCD;     // 30 (240 % 8 == 0 -> bijective)
static constexpr float EPSF = 1e-9f;

// k order matches reference PADS: (di,dj) =
// k:   0       1       2       3       4       5       6       7
//    (+1,+1) (+1,0) (+1,-1) (0,+1) (0,-1) (-1,+1) (-1,0) (-1,-1)
static constexpr int DI[8] = { 1, 1, 1, 0, 0, -1, -1, -1 };
static constexpr int DJ[8] = { 1, 0, -1, 1, -1, 1, 0, -1 };

static __device__ __forceinline__ int iclamp(int v, int lo, int hi) {
    return min(max(v, lo), hi);
}

// Single launch, zero inter-block communication: each block owns a 64x64
// output tile and carries the full 24-step halo (112x112 region) in LDS.
//
// Round-5 fix vs round-4: the ONLY change is the register-budget attribute.
// Evidence across rounds 3/4: __launch_bounds__'s 2nd arg behaves as
// blocks-per-CU (CUDA semantics) in hipcc's occupancy target — (512,2) gave
// 128 VGPRs, (1024,4) gave 64 — and the allocator's target ignores the LDS
// limit (98 KB -> only 1 block/CU is physically possible). Result: ~75 MB
// of scratch spill (WRITE_SIZE 79 MB vs ideal 4 MB). amdgpu_waves_per_eu(4,4)
// pins exactly 4 waves/EU = our single 16-wave block -> 128-VGPR budget;
// persistent state (wh 48 + Cc 12 + pr 12 = 72) + step temps ~25 fits.
//
//  - d ping-pongs in LDS (2 x 112^2 fp32 = 98 KB -> 1 block/CU).
//  - Weights computed inline from guidance (normalization + sparse clamp
//    baked in), packed fp16 in registers for all 24 steps.
//  - Shrinking active set: step s only computes pixels with ring >= s;
//    step 24's active set is exactly the valid 64x64 center.
//  - Ring-0 pixels staged once into sd[0]; only read at step 1 (induction:
//    ring-r values read at step s come from the step-(s-1) buffer).
//  - Out-of-image region pixels hold clamped duplicates; they never reach
//    the center because image-boundary pixels have weight 0 toward
//    out-of-bounds neighbors (zero-padded guidance).
//  - s-loop NOT unrolled (I-cache); q-loops unrolled so arrays stay in regs.
__global__ __launch_bounds__(BLOCK)
__attribute__((amdgpu_waves_per_eu(4, 4)))
void mega(
    const float* __restrict__ g,
    const float* __restrict__ blur,
    const float* __restrict__ sparse,
    float* __restrict__ out)
{
    __shared__ float sd[2][RR];

    const int tid = threadIdx.x;
    // XCD-aware bijective swizzle: consecutive tiles (which share halo
    // guidance/blur reads) land on the same XCD's private L2.
    int bx = ((int)blockIdx.x % NXCD) * CHUNK + (int)blockIdx.x / NXCD;
    const int tj = bx % TJ; bx /= TJ;
    const int ti = bx % TI;
    const int b  = bx / TI;
    const int oi = ti * TILE - T;          // region origin (image coords)
    const int oj = tj * TILE - T;

    const float* blurb = blur + (size_t)b * HW;
    const float* gb    = g    + (size_t)b * 8 * HW;

    // --- stage d0 = blur over the whole region (image-clamped) ---
#pragma unroll
    for (int q = 0; q < PPQ; q++) {
        int p = tid + q * BLOCK;
        if (p < RR) {
            int ri = p / R, rj = p - ri * R;
            int gi = iclamp(oi + ri, 0, Hh - 1);
            int gj = iclamp(oj + rj, 0, Ww - 1);
            sd[0][p] = blurb[gi * Ww + gj];
        }
    }

    // --- weights (packed fp16) + C for interior pixels; registers for all
    // 24 steps. pr packed: low 16 = region offset, high 16 = ring dist ---
    __half2 wh[PPI][4];
    float   Cc[PPI];
    int     pr[PPI];
#pragma unroll
    for (int q = 0; q < PPI; q++) {
        int pi = tid + q * BLOCK;
        if (pi < NINT) {
            int r0 = pi / ISIDE;
            int ri = 1 + r0, rj = 1 + (pi - r0 * ISIDE);
            int rng = min(min(ri, R - 1 - ri), min(rj, R - 1 - rj));
            pr[q] = (ri * R + rj) | (rng << 16);
            int gi = iclamp(oi + ri, 0, Hh - 1);
            int gj = iclamp(oj + rj, 0, Ww - 1);
            float v[8];
            float a = EPSF;
#pragma unroll
            for (int k = 0; k < 8; k++) {
                int ii = gi + DI[k], jj = gj + DJ[k];
                float gv = 0.0f;
                if (ii >= 0 && ii < Hh && jj >= 0 && jj < Ww)
                    gv = gb[k * HW + ii * Ww + jj];
                v[k] = gv;
                a += fabsf(gv);
            }
            float inv = 1.0f / a, gs = 0.0f;
#pragma unroll
            for (int k = 0; k < 8; k++) { v[k] *= inv; gs += v[k]; }
            int idx = gi * Ww + gj;
            float rawv = blurb[idx];
            bool m = sparse[b * HW + idx] > 0.0f;  // sparse>=0; sign(s)==1 iff s>0
            Cc[q] = m ? rawv : (1.0f - gs) * rawv;
#pragma unroll
            for (int k = 0; k < 4; k++) {
                __half2 h;
                h.x = __float2half(m ? 0.0f : v[2 * k]);
                h.y = __float2half(m ? 0.0f : v[2 * k + 1]);
                wh[q][k] = h;
            }
        } else {
            pr[q] = 0; Cc[q] = 0.0f;
#pragma unroll
            for (int k = 0; k < 4; k++) wh[q][k] = __floats2half2_rn(0.0f, 0.0f);
        }
    }
    __syncthreads();

    // --- steps 1..T-1 in LDS; step s touches only ring >= s ---
    int cur = 0;
#pragma unroll 1
    for (int s = 1; s < T; ++s) {
        const float* s0 = sd[cur];
        float* s1 = sd[cur ^ 1];
#pragma unroll
        for (int q = 0; q < PPI; q++) {
            if ((pr[q] >> 16) >= s) {
                int p = pr[q] & 0xffff;
                float2 w01 = __half22float2(wh[q][0]);
                float2 w23 = __half22float2(wh[q][1]);
                float2 w45 = __half22float2(wh[q][2]);
                float2 w67 = __half22float2(wh[q][3]);
                float v = Cc[q]
                    + w01.x * s0[p + R + 1] + w01.y * s0[p + R]
                    + w23.x * s0[p + R - 1] + w23.y * s0[p + 1]
                    + w45.x * s0[p - 1]     + w45.y * s0[p - R + 1]
                    + w67.x * s0[p - R]     + w67.y * s0[p - R - 1];
                s1[p] = v;
            }
        }
        __syncthreads();
        cur ^= 1;
    }

    // --- step T: ring >= T is exactly the valid 64x64 center; write out ---
    const float* s0 = sd[cur];
#pragma unroll
    for (int q = 0; q < PPI; q++) {
        if ((pr[q] >> 16) >= T) {
            int p = pr[q] & 0xffff;
            float2 w01 = __half22float2(wh[q][0]);
            float2 w23 = __half22float2(wh[q][1]);
            float2 w45 = __half22float2(wh[q][2]);
            float2 w67 = __half22float2(wh[q][3]);
            float v = Cc[q]
                + w01.x * s0[p + R + 1] + w01.y * s0[p + R]
                + w23.x * s0[p + R - 1] + w23.y * s0[p + 1]
                + w45.x * s0[p - 1]     + w45.y * s0[p - R + 1]
                + w67.x * s0[p - R]     + w67.y * s0[p - R - 1];
            int ri = p / R, rj = p - ri * R;
            out[b * HW + (oi + ri) * Ww + (oj + rj)] = v;
        }
    }
}

extern "C" void kernel_launch(void* const* d_in, const int* in_sizes, int n_in,
                              void* d_out, int out_size, void* d_ws, size_t ws_size,
                              hipStream_t stream) {
    const float* guidance = (const float*)d_in[0];
    const float* blur     = (const float*)d_in[1];
    const float* sparse   = (const float*)d_in[2];
    float* out = (float*)d_out;

    mega<<<GRID, BLOCK, 0, stream>>>(guidance, blur, sparse, out);
}

// Round 6
// 175.537 us; speedup vs baseline: 1.0162x; 1.0162x over previous
//
#include <hip/hip_runtime.h>
#include <hip/hip_fp16.h>

static constexpr int Hh = 384;
static constexpr int Ww = 1280;
static constexpr int HW = Hh * Ww;            // 491520
static constexpr int TILE = 64;               // output tile side
static constexpr int T = 24;                  // ALL steps fused, single launch
static constexpr int R = TILE + 2 * T;        // 112: region side incl. 24-step halo
static constexpr int RR = R * R;              // 12544
static constexpr int ISIDE = R - 2;           // 110
static constexpr int NINT = ISIDE * ISIDE;    // 12100 interior pixels
static constexpr int BLOCK = 1024;
static constexpr int PPQ = (RR + BLOCK - 1) / BLOCK;    // 13 region px / thread
static constexpr int PPI = (NINT + BLOCK - 1) / BLOCK;  // 12 interior px / thread
static constexpr int TI = Hh / TILE;          // 6
static constexpr int TJ = Ww / TILE;          // 20
static constexpr int GRID = 2 * TI * TJ;      // 240 fully independent blocks
static constexpr int NXCD = 8;
static constexpr int CHUNK = GRID / NXCD;     // 30 (240 % 8 == 0 -> bijective)
static constexpr float EPSF = 1e-9f;

// k order matches reference PADS: (di,dj) =
// k:   0       1       2       3       4       5       6       7
//    (+1,+1) (+1,0) (+1,-1) (0,+1) (0,-1) (-1,+1) (-1,0) (-1,-1)
static constexpr int DI[8] = { 1, 1, 1, 0, 0, -1, -1, -1 };
static constexpr int DJ[8] = { 1, 0, -1, 1, -1, 1, 0, -1 };

static __device__ __forceinline__ int iclamp(int v, int lo, int hi) {
    return min(max(v, lo), hi);
}

// Single launch, zero inter-block communication: each block owns a 64x64
// output tile and carries the full 24-step halo (112x112 region) in LDS.
//
// Round-6: the ONLY change vs round 5 is __launch_bounds__(1024, 1).
// Cross-round evidence on hipcc's occupancy targeting:
//   (512,2) -> 128 VGPR; (1024,4) -> 64; (1024)+amdgpu_waves_per_eu(4,4)
//   -> 64 (attribute silently ignored).
// Consistent model: 2nd arg = max BLOCKS/CU (CUDA semantics), target waves =
// blocks*block_waves clamped to 32/CU, LDS NOT considered (98 KB already
// limits us to 1 block/CU). Bare (1024) defaulted to 2 blocks/CU -> 32 waves
// -> 64-VGPR budget -> ~75 MB scratch spill (WRITE_SIZE 79 MB vs 4 MB ideal).
// (1024,1): 1 block/CU = 16 waves = 4 waves/SIMD -> 128-VGPR budget, which
// is also the architectural max for a 1024-thread block. Persistent state
// (wh 48 + Cc 12 + pr 12 = 72) + step temps ~30 fits under 128.
//
//  - d ping-pongs in LDS (2 x 112^2 fp32 = 98 KB -> 1 block/CU).
//  - Weights computed inline from guidance (normalization + sparse clamp
//    baked in), packed fp16 in registers for all 24 steps.
//  - Shrinking active set: step s only computes pixels with ring >= s;
//    step 24's active set is exactly the valid 64x64 center.
//  - Ring-0 pixels staged once into sd[0]; only read at step 1 (induction:
//    ring-r values read at step s come from the step-(s-1) buffer).
//  - Out-of-image region pixels hold clamped duplicates; they never reach
//    the center because image-boundary pixels have weight 0 toward
//    out-of-bounds neighbors (zero-padded guidance).
//  - s-loop NOT unrolled (I-cache); q-loops unrolled so arrays stay in regs.
__global__ __launch_bounds__(BLOCK, 1)
void mega(
    const float* __restrict__ g,
    const float* __restrict__ blur,
    const float* __restrict__ sparse,
    float* __restrict__ out)
{
    __shared__ float sd[2][RR];

    const int tid = threadIdx.x;
    // XCD-aware bijective swizzle: consecutive tiles (which share halo
    // guidance/blur reads) land on the same XCD's private L2.
    int bx = ((int)blockIdx.x % NXCD) * CHUNK + (int)blockIdx.x / NXCD;
    const int tj = bx % TJ; bx /= TJ;
    const int ti = bx % TI;
    const int b  = bx / TI;
    const int oi = ti * TILE - T;          // region origin (image coords)
    const int oj = tj * TILE - T;

    const float* blurb = blur + (size_t)b * HW;
    const float* gb    = g    + (size_t)b * 8 * HW;

    // --- stage d0 = blur over the whole region (image-clamped) ---
#pragma unroll
    for (int q = 0; q < PPQ; q++) {
        int p = tid + q * BLOCK;
        if (p < RR) {
            int ri = p / R, rj = p - ri * R;
            int gi = iclamp(oi + ri, 0, Hh - 1);
            int gj = iclamp(oj + rj, 0, Ww - 1);
            sd[0][p] = blurb[gi * Ww + gj];
        }
    }

    // --- weights (packed fp16) + C for interior pixels; registers for all
    // 24 steps. pr packed: low 16 = region offset, high 16 = ring dist ---
    __half2 wh[PPI][4];
    float   Cc[PPI];
    int     pr[PPI];
#pragma unroll
    for (int q = 0; q < PPI; q++) {
        int pi = tid + q * BLOCK;
        if (pi < NINT) {
            int r0 = pi / ISIDE;
            int ri = 1 + r0, rj = 1 + (pi - r0 * ISIDE);
            int rng = min(min(ri, R - 1 - ri), min(rj, R - 1 - rj));
            pr[q] = (ri * R + rj) | (rng << 16);
            int gi = iclamp(oi + ri, 0, Hh - 1);
            int gj = iclamp(oj + rj, 0, Ww - 1);
            float v[8];
            float a = EPSF;
#pragma unroll
            for (int k = 0; k < 8; k++) {
                int ii = gi + DI[k], jj = gj + DJ[k];
                float gv = 0.0f;
                if (ii >= 0 && ii < Hh && jj >= 0 && jj < Ww)
                    gv = gb[k * HW + ii * Ww + jj];
                v[k] = gv;
                a += fabsf(gv);
            }
            float inv = 1.0f / a, gs = 0.0f;
#pragma unroll
            for (int k = 0; k < 8; k++) { v[k] *= inv; gs += v[k]; }
            int idx = gi * Ww + gj;
            float rawv = blurb[idx];
            bool m = sparse[b * HW + idx] > 0.0f;  // sparse>=0; sign(s)==1 iff s>0
            Cc[q] = m ? rawv : (1.0f - gs) * rawv;
#pragma unroll
            for (int k = 0; k < 4; k++) {
                __half2 h;
                h.x = __float2half(m ? 0.0f : v[2 * k]);
                h.y = __float2half(m ? 0.0f : v[2 * k + 1]);
                wh[q][k] = h;
            }
        } else {
            pr[q] = 0; Cc[q] = 0.0f;
#pragma unroll
            for (int k = 0; k < 4; k++) wh[q][k] = __floats2half2_rn(0.0f, 0.0f);
        }
    }
    __syncthreads();

    // --- steps 1..T-1 in LDS; step s touches only ring >= s ---
    int cur = 0;
#pragma unroll 1
    for (int s = 1; s < T; ++s) {
        const float* s0 = sd[cur];
        float* s1 = sd[cur ^ 1];
#pragma unroll
        for (int q = 0; q < PPI; q++) {
            if ((pr[q] >> 16) >= s) {
                int p = pr[q] & 0xffff;
                float2 w01 = __half22float2(wh[q][0]);
                float2 w23 = __half22float2(wh[q][1]);
                float2 w45 = __half22float2(wh[q][2]);
                float2 w67 = __half22float2(wh[q][3]);
                float v = Cc[q]
                    + w01.x * s0[p + R + 1] + w01.y * s0[p + R]
                    + w23.x * s0[p + R - 1] + w23.y * s0[p + 1]
                    + w45.x * s0[p - 1]     + w45.y * s0[p - R + 1]
                    + w67.x * s0[p - R]     + w67.y * s0[p - R - 1];
                s1[p] = v;
            }
        }
        __syncthreads();
        cur ^= 1;
    }

    // --- step T: ring >= T is exactly the valid 64x64 center; write out ---
    const float* s0 = sd[cur];
#pragma unroll
    for (int q = 0; q < PPI; q++) {
        if ((pr[q] >> 16) >= T) {
            int p = pr[q] & 0xffff;
            float2 w01 = __half22float2(wh[q][0]);
            float2 w23 = __half22float2(wh[q][1]);
            float2 w45 = __half22float2(wh[q][2]);
            float2 w67 = __half22float2(wh[q][3]);
            float v = Cc[q]
                + w01.x * s0[p + R + 1] + w01.y * s0[p + R]
                + w23.x * s0[p + R - 1] + w23.y * s0[p + 1]
                + w45.x * s0[p - 1]     + w45.y * s0[p - R + 1]
                + w67.x * s0[p - R]     + w67.y * s0[p - R - 1];
            int ri = p / R, rj = p - ri * R;
            out[b * HW + (oi + ri) * Ww + (oj + rj)] = v;
        }
    }
}

extern "C" void kernel_launch(void* const* d_in, const int* in_sizes, int n_in,
                              void* d_out, int out_size, void* d_ws, size_t ws_size,
                              hipStream_t stream) {
    const float* guidance = (const float*)d_in[0];
    const float* blur     = (const float*)d_in[1];
    const float* sparse   = (const float*)d_in[2];
    float* out = (float*)d_out;

    mega<<<GRID, BLOCK, 0, stream>>>(guidance, blur, sparse, out);
}